// Round 1
// baseline (389.339 us; speedup 1.0000x reference)
//
#include <hip/hip_runtime.h>

#define T_SEQ 512
#define ISZ 8
#define HID 64
#define L2E 1.44269504088896340736f

typedef __bf16 bf16x8 __attribute__((ext_vector_type(8)));
typedef float  f32x4  __attribute__((ext_vector_type(4)));

__device__ __forceinline__ float exp2_hw(float x) {
    float r; asm("v_exp_f32 %0, %1" : "=v"(r) : "v"(x)); return r;
}
__device__ __forceinline__ unsigned cvt_pk_bf16(float a, float b) {
    unsigned r; asm("v_cvt_pk_bf16_f32 %0, %1, %2" : "=v"(r) : "v"(a), "v"(b)); return r;
}

// v8: 256 blocks x 16 batch rows, 4 waves. Each block runs TWO independent
// 8-row LSTM groups (A,B) in one instruction stream (2-way in-wave ILP):
// one barrier per superstep advances both groups, so each group's serial
// chain (ds_read -> MFMA accumulate chain -> trans-heavy activation ->
// ds_write) hides under the partner group's issue. Weight B-fragments are
// shared between groups. Asymmetric per-step jobs spread across waves:
// w0 = dense A + store A, w1 = dense B + store B, w2 = x-producer B,
// w3 = x-producer A. Everything else (M-packed hi/lo split precision,
// XOR-swizzled h planes, bias-seeded C, fused-rcp activations, rolling
// float4 output windows, raw barrier with lgkmcnt-only drain) is v7.
__global__ __launch_bounds__(256, 1) void lstm_v8_kernel(
    const float* __restrict__ x,
    const float* __restrict__ W_ih,
    const float* __restrict__ W_hh,
    const float* __restrict__ b_ih,
    const float* __restrict__ b_hh,
    const float* __restrict__ W_dense,
    const float* __restrict__ b_dense,
    float* __restrict__ out)
{
    __shared__ __align__(16) __bf16 hplA[2][16 * 64];
    __shared__ __align__(16) __bf16 hplB[2][16 * 64];
    __shared__ __align__(16) __bf16 xsA[2][160];
    __shared__ __align__(16) __bf16 xsB[2][160];
    __shared__ __align__(16) __bf16 xz[8];

    const int tid  = threadIdx.x;
    const int lane = tid & 63;
    const int w    = tid >> 6;
    const int q    = lane >> 4;          // k-chunk: k = 32s + 8q + e
    const int sub  = lane & 15;          // A row / B col
    const int br   = 2 * (sub >> 2) + (sub & 1);   // batch row carried by A-row sub
    const bool isLo = (sub & 2) != 0;
    const long b0  = (long)blockIdx.x * 16;        // A: rows b0..b0+7, B: b0+8..b0+15

    // ---------------- B fragments: bf16(W * gate-scale), SHARED A/B ----------
    bf16x8 Bg[4][3];
    float biasg[4];
    #pragma unroll
    for (int g = 0; g < 4; ++g) {
        const int m = g * HID + 16 * w + sub;
        const float sc = (g == 2) ? (2.0f * L2E) : (-L2E);
        biasg[g] = (b_ih[m] + b_hh[m]) * sc;
        #pragma unroll
        for (int s = 0; s < 3; ++s) {
            #pragma unroll
            for (int e = 0; e < 8; ++e) {
                const int k = 32 * s + 8 * q + e;
                float v = 0.0f;
                if (k < HID)            v = W_hh[m * HID + k] * sc;
                else if (k < HID + ISZ) v = W_ih[m * ISZ + (k - HID)] * sc;
                Bg[g][s][e] = (__bf16)v;
            }
        }
    }
    f32x4 Cs[4];
    #pragma unroll
    for (int g = 0; g < 4; ++g) { Cs[g][0] = biasg[g]; Cs[g][1] = biasg[g]; Cs[g][2] = 0.f; Cs[g][3] = 0.f; }

    // dense weights: col 0 = hi, col 1 = lo residual
    bf16x8 Bwd[2];
    #pragma unroll
    for (int s = 0; s < 2; ++s) {
        #pragma unroll
        for (int e = 0; e < 8; ++e) {
            const int k = 32 * s + 8 * q + e;
            const float wv = W_dense[k];
            const __bf16 whi = (__bf16)wv;
            float val = (sub == 0) ? (float)whi : (sub == 1) ? (wv - (float)whi) : 0.0f;
            Bwd[s][e] = (__bf16)val;
        }
    }

    // zero h(-1) planes and the zero x-frag
    for (int i = tid; i < 512; i += 256) {
        ((float*)&hplA[1][0])[i] = 0.0f;
        ((float*)&hplB[1][0])[i] = 0.0f;
    }
    if (tid < 4) ((float*)&xz[0])[tid] = 0.0f;

    // ---------------- x producers (w3 -> A, w2 -> B; lanes 0-15) -------------
    const int  pr = lane >> 1, ph = lane & 1;
    const float* xbaseA = x + ((b0 + pr) * (long)T_SEQ) * ISZ + ph * 4;
    const float* xbaseB = x + ((b0 + 8 + pr) * (long)T_SEQ) * ISZ + ph * 4;
    const int  xoffH = pr * 8 + ph * 4;
    const int  xoffL = 64 + xoffH;

#define XWRITE(XV, DST)                                                      \
    {                                                                        \
        unsigned h01 = cvt_pk_bf16(XV.x, XV.y);                              \
        unsigned h23 = cvt_pk_bf16(XV.z, XV.w);                              \
        float f0 = __uint_as_float(h01 << 16);                               \
        float f1 = __uint_as_float(h01 & 0xffff0000u);                       \
        float f2 = __uint_as_float(h23 << 16);                               \
        float f3 = __uint_as_float(h23 & 0xffff0000u);                       \
        unsigned l01 = cvt_pk_bf16(XV.x - f0, XV.y - f1);                    \
        unsigned l23 = cvt_pk_bf16(XV.z - f2, XV.w - f3);                    \
        uint2 hh2; hh2.x = h01; hh2.y = h23;                                 \
        uint2 ll2; ll2.x = l01; ll2.y = l23;                                 \
        *(uint2*)&(DST)[xoffH] = hh2;                                        \
        *(uint2*)&(DST)[xoffL] = ll2;                                        \
    }

    if (w == 3 && lane < 16) { float4 xv = *(const float4*)xbaseA; XWRITE(xv, &xsA[0][0]) }
    if (w == 2 && lane < 16) { float4 xv = *(const float4*)xbaseB; XWRITE(xv, &xsB[0][0]) }

    // consumer x-frag pointers (invariant; one per plane per group)
    const __bf16* xrdA0 = (q == 0) ? &xsA[0][(isLo ? 64 : 0) + br * 8] : &xz[0];
    const __bf16* xrdA1 = (q == 0) ? &xsA[1][(isLo ? 64 : 0) + br * 8] : &xz[0];
    const __bf16* xrdB0 = (q == 0) ? &xsB[0][(isLo ? 64 : 0) + br * 8] : &xz[0];
    const __bf16* xrdB1 = (q == 0) ? &xsB[1][(isLo ? 64 : 0) + br * 8] : &xz[0];

    // ---------------- state ----------------
    float cA0 = 0.f, cA1 = 0.f, cB0 = 0.f, cB1 = 0.f;
    const float bd  = b_dense[0];
    const f32x4 Z   = {0.f, 0.f, 0.f, 0.f};
    const int  swz  = (sub & 7) << 3;
    const int  jme  = 16 * w + sub;

    float s0A[4], s1A[4], s0B[4], s1B[4];
    #pragma unroll
    for (int i = 0; i < 4; ++i) { s0A[i] = 0.f; s1A[i] = 0.f; s0B[i] = 0.f; s1B[i] = 0.f; }

    __syncthreads();

#define MF(A, B, C) __builtin_amdgcn_mfma_f32_16x16x32_bf16(A, B, C, 0, 0, 0)

#define ACT(A0, A1, A2, A3, CC0, CC1, HW)                                    \
    _Pragma("unroll")                                                        \
    for (int i = 0; i < 2; ++i) {                                            \
        const float gi = A0[i] + A0[2 + i];                                  \
        const float gf = A1[i] + A1[2 + i];                                  \
        const float gg = A2[i] + A2[2 + i];                                  \
        const float go = A3[i] + A3[2 + i];                                  \
        const float eA = exp2_hw(gi);                                        \
        const float eF = exp2_hw(gf);                                        \
        const float eB = exp2_hw(gg);                                        \
        const float ig = (eB - 1.0f) *                                       \
            __builtin_amdgcn_rcpf((1.0f + eA) * (1.0f + eB));                \
        const float ff = __builtin_amdgcn_rcpf(1.0f + eF);                   \
        float cc = i ? CC1 : CC0;                                            \
        cc = fmaf(ff, cc, ig);                                               \
        if (i) CC1 = cc; else CC0 = cc;                                      \
        const float eO = exp2_hw(go);                                        \
        const float eC = exp2_hw(fminf(cc * (2.0f * L2E), 80.0f));           \
        const float hh = (eC - 1.0f) *                                       \
            __builtin_amdgcn_rcpf((1.0f + eO) * (1.0f + eC));                \
        const __bf16 hi = (__bf16)hh;                                        \
        const __bf16 lo = (__bf16)(hh - (float)hi);                          \
        const int rh = 4 * q + i;                                            \
        const int rl = rh + 2;                                               \
        (HW)[rh * 64 + (jme ^ ((rh & 7) << 3))] = hi;                        \
        (HW)[rl * 64 + (jme ^ ((rl & 7) << 3))] = lo;                        \
    }

#define DENSE(AH0, AH1, S0, S1, PP)                                          \
    {                                                                        \
        f32x4 oz = MF(AH0, Bwd[0], Z);                                       \
        oz = MF(AH1, Bwd[1], oz);                                            \
        float v0 = oz[0] + oz[2];                                            \
        float v1 = oz[1] + oz[3];                                            \
        v0 += __shfl_xor(v0, 1);                                             \
        v1 += __shfl_xor(v1, 1);                                             \
        (S0)[((PP) + 3) & 3] = v0;                                           \
        (S1)[((PP) + 3) & 3] = v1;                                           \
    }

    // P = unroll pos, PB = h plane holding h(t-1), XRA/XRB = x-frag ptrs,
    // XW = strip plane to write x(t+1) into (all compile-time per site).
#define STEP(P, PB, XRA, XRB, XW)                                            \
    {                                                                        \
        const int t = tb + P;                                                \
        float4 xvA, xvB;                                                     \
        if (w == 3 && lane < 16) {                                           \
            const int tn = (t + 1 < T_SEQ) ? (t + 1) : (T_SEQ - 1);          \
            xvA = *(const float4*)(xbaseA + (long)tn * ISZ);                 \
        }                                                                    \
        if (w == 2 && lane < 16) {                                           \
            const int tn = (t + 1 < T_SEQ) ? (t + 1) : (T_SEQ - 1);          \
            xvB = *(const float4*)(xbaseB + (long)tn * ISZ);                 \
        }                                                                    \
        bf16x8 AxA  = *(const bf16x8*)(XRA);                                 \
        bf16x8 AxB  = *(const bf16x8*)(XRB);                                 \
        bf16x8 AhA0 = *(const bf16x8*)&hplA[PB][sub * 64 + ((8 * q)      ^ swz)]; \
        bf16x8 AhA1 = *(const bf16x8*)&hplA[PB][sub * 64 + ((32 + 8 * q) ^ swz)]; \
        bf16x8 AhB0 = *(const bf16x8*)&hplB[PB][sub * 64 + ((8 * q)      ^ swz)]; \
        bf16x8 AhB1 = *(const bf16x8*)&hplB[PB][sub * 64 + ((32 + 8 * q) ^ swz)]; \
        __builtin_amdgcn_s_setprio(1);                                       \
        f32x4 aA0 = MF(AxA, Bg[0][2], Cs[0]);                                \
        f32x4 aB0 = MF(AxB, Bg[0][2], Cs[0]);                                \
        f32x4 aA1 = MF(AxA, Bg[1][2], Cs[1]);                                \
        f32x4 aB1 = MF(AxB, Bg[1][2], Cs[1]);                                \
        f32x4 aA2 = MF(AxA, Bg[2][2], Cs[2]);                                \
        f32x4 aB2 = MF(AxB, Bg[2][2], Cs[2]);                                \
        f32x4 aA3 = MF(AxA, Bg[3][2], Cs[3]);                                \
        f32x4 aB3 = MF(AxB, Bg[3][2], Cs[3]);                                \
        aA0 = MF(AhA0, Bg[0][0], aA0); aB0 = MF(AhB0, Bg[0][0], aB0);        \
        aA1 = MF(AhA0, Bg[1][0], aA1); aB1 = MF(AhB0, Bg[1][0], aB1);        \
        aA2 = MF(AhA0, Bg[2][0], aA2); aB2 = MF(AhB0, Bg[2][0], aB2);        \
        aA3 = MF(AhA0, Bg[3][0], aA3); aB3 = MF(AhB0, Bg[3][0], aB3);        \
        aA0 = MF(AhA1, Bg[0][1], aA0); aB0 = MF(AhB1, Bg[0][1], aB0);        \
        aA1 = MF(AhA1, Bg[1][1], aA1); aB1 = MF(AhB1, Bg[1][1], aB1);        \
        aA2 = MF(AhA1, Bg[2][1], aA2); aB2 = MF(AhB1, Bg[2][1], aB2);        \
        aA3 = MF(AhA1, Bg[3][1], aA3); aB3 = MF(AhB1, Bg[3][1], aB3);        \
        __builtin_amdgcn_s_setprio(0);                                       \
        /* dense o(t-1): group A on wave 0, group B on wave 1 */             \
        if (w == 0) DENSE(AhA0, AhA1, s0A, s1A, P)                           \
        if (w == 1) DENSE(AhB0, AhB1, s0B, s1B, P)                           \
        /* activations: A then B; independent chains interleave in sched */  \
        ACT(aA0, aA1, aA2, aA3, cA0, cA1, &hplA[PB ^ 1][0])                  \
        ACT(aB0, aB1, aB2, aB3, cB0, cB1, &hplB[PB ^ 1][0])                  \
        /* producers: convert + write x(t+1) strips (load latency hidden) */ \
        if (w == 3 && lane < 16) XWRITE(xvA, &xsA[XW][0])                    \
        if (w == 2 && lane < 16) XWRITE(xvB, &xsB[XW][0])                    \
        /* batched coalesced stores: window [tb-4, tb-1], once per 4 steps */\
        if (P == 0 && tb >= 4) {                                             \
            if (w == 0 && sub == 0) {                                        \
                *(float4*)&out[(b0 + 2 * q) * T_SEQ + tb - 4] =              \
                    make_float4(s0A[0] + bd, s0A[1] + bd, s0A[2] + bd, s0A[3] + bd); \
                *(float4*)&out[(b0 + 2 * q + 1) * T_SEQ + tb - 4] =          \
                    make_float4(s1A[0] + bd, s1A[1] + bd, s1A[2] + bd, s1A[3] + bd); \
            }                                                                \
            if (w == 1 && sub == 0) {                                        \
                *(float4*)&out[(b0 + 8 + 2 * q) * T_SEQ + tb - 4] =          \
                    make_float4(s0B[0] + bd, s0B[1] + bd, s0B[2] + bd, s0B[3] + bd); \
                *(float4*)&out[(b0 + 8 + 2 * q + 1) * T_SEQ + tb - 4] =      \
                    make_float4(s1B[0] + bd, s1B[1] + bd, s1B[2] + bd, s1B[3] + bd); \
            }                                                                \
        }                                                                    \
        asm volatile("s_waitcnt lgkmcnt(0)" ::: "memory");                   \
        __builtin_amdgcn_s_barrier();                                        \
        __builtin_amdgcn_sched_barrier(0);                                   \
    }

    for (int tb = 0; tb < T_SEQ; tb += 4) {
        STEP(0, 1, xrdA0, xrdB0, 1)
        STEP(1, 0, xrdA1, xrdB1, 0)
        STEP(2, 1, xrdA0, xrdB0, 1)
        STEP(3, 0, xrdA1, xrdB1, 0)
    }
#undef STEP

    // ---- epilogue: o(511) from h(511) (plane 1); store window [508, 511] ----
    if (w == 0) {
        bf16x8 Eh0 = *(const bf16x8*)&hplA[1][sub * 64 + ((8 * q)      ^ swz)];
        bf16x8 Eh1 = *(const bf16x8*)&hplA[1][sub * 64 + ((32 + 8 * q) ^ swz)];
        f32x4 oz = MF(Eh0, Bwd[0], Z);
        oz = MF(Eh1, Bwd[1], oz);
        float v0 = oz[0] + oz[2];
        float v1 = oz[1] + oz[3];
        v0 += __shfl_xor(v0, 1);
        v1 += __shfl_xor(v1, 1);
        s0A[3] = v0;
        s1A[3] = v1;
        if (sub == 0) {
            *(float4*)&out[(b0 + 2 * q) * T_SEQ + (T_SEQ - 4)] =
                make_float4(s0A[0] + bd, s0A[1] + bd, s0A[2] + bd, s0A[3] + bd);
            *(float4*)&out[(b0 + 2 * q + 1) * T_SEQ + (T_SEQ - 4)] =
                make_float4(s1A[0] + bd, s1A[1] + bd, s1A[2] + bd, s1A[3] + bd);
        }
    }
    if (w == 1) {
        bf16x8 Eh0 = *(const bf16x8*)&hplB[1][sub * 64 + ((8 * q)      ^ swz)];
        bf16x8 Eh1 = *(const bf16x8*)&hplB[1][sub * 64 + ((32 + 8 * q) ^ swz)];
        f32x4 oz = MF(Eh0, Bwd[0], Z);
        oz = MF(Eh1, Bwd[1], oz);
        float v0 = oz[0] + oz[2];
        float v1 = oz[1] + oz[3];
        v0 += __shfl_xor(v0, 1);
        v1 += __shfl_xor(v1, 1);
        s0B[3] = v0;
        s1B[3] = v1;
        if (sub == 0) {
            *(float4*)&out[(b0 + 8 + 2 * q) * T_SEQ + (T_SEQ - 4)] =
                make_float4(s0B[0] + bd, s0B[1] + bd, s0B[2] + bd, s0B[3] + bd);
            *(float4*)&out[(b0 + 8 + 2 * q + 1) * T_SEQ + (T_SEQ - 4)] =
                make_float4(s1B[0] + bd, s1B[1] + bd, s1B[2] + bd, s1B[3] + bd);
        }
    }
#undef MF
#undef ACT
#undef DENSE
#undef XWRITE
}

extern "C" void kernel_launch(void* const* d_in, const int* in_sizes, int n_in,
                              void* d_out, int out_size, void* d_ws, size_t ws_size,
                              hipStream_t stream) {
    const float* x       = (const float*)d_in[0];
    const float* W_ih    = (const float*)d_in[1];
    const float* W_hh    = (const float*)d_in[2];
    const float* b_ih    = (const float*)d_in[3];
    const float* b_hh    = (const float*)d_in[4];
    const float* W_dense = (const float*)d_in[5];
    const float* b_dense = (const float*)d_in[6];
    float* out = (float*)d_out;

    const int B = in_sizes[0] / (T_SEQ * ISZ);   // 4096
    const int blocks = B / 16;                    // 256 blocks -> 1 block/CU, 2-way in-wave ILP
    lstm_v8_kernel<<<blocks, 256, 0, stream>>>(x, W_ih, W_hh, b_ih, b_hh,
                                               W_dense, b_dense, out);
}